// Round 1
// baseline (469.159 us; speedup 1.0000x reference)
//
#include <hip/hip_runtime.h>
#include <hip/hip_bf16.h>

typedef __attribute__((ext_vector_type(8))) short short8;
typedef __attribute__((ext_vector_type(4))) float f32x4;

#define XT_IMG_BYTES (66*66*256*2)      // 2,230,272 per sample
#define XT_TOTAL_BYTES (32*XT_IMG_BYTES) // 71,368,704
#define WM_ROW_BYTES (2304*2)            // 4608
#define WM_IMG_BYTES (256*WM_ROW_BYTES)  // 1,179,648

static __device__ __forceinline__ void async16(void* lds, const void* g) {
  __builtin_amdgcn_global_load_lds((const __attribute__((address_space(1))) void*)g,
                                   (__attribute__((address_space(3))) void*)lds, 16, 0, 0);
}
static __device__ __forceinline__ ushort f2bf(float f) {
  __hip_bfloat16 h = __float2bfloat16(f);
  return *reinterpret_cast<ushort*>(&h);
}

// ---------------- zero the padded xT region (covers pad borders) ----------------
__global__ __launch_bounds__(256) void k_zero(uint4* __restrict__ p) {
  size_t i = (size_t)blockIdx.x * 256 + threadIdx.x;
  p[i] = make_uint4(0u, 0u, 0u, 0u);
}

// ---------------- x [b][c][h][w] fp32 -> xT [b][h+1][w+1][c] bf16 (interior) ----
__global__ __launch_bounds__(256) void k_xpose(const float* __restrict__ x,
                                               ushort* __restrict__ xT) {
  __shared__ float lds[64][65];
  const int bx = blockIdx.x;
  const int b  = bx >> 8;
  const int h  = (bx >> 2) & 63;
  const int c0 = (bx & 3) << 6;
  const int t  = threadIdx.x;
  const int tw = t & 63, tg = t >> 6;
  const float* xp = x + (size_t)(b * 256 + c0) * 4096 + h * 64 + tw;
#pragma unroll
  for (int j = 0; j < 16; ++j) {
    int il = j * 4 + tg;
    lds[il][tw] = xp[(size_t)il * 4096];
  }
  __syncthreads();
  const int ic = t & 63, wg = t >> 6;
  ushort* op = xT + (size_t)b * (66 * 66 * 256) + ((size_t)(h + 1) * 66 + 1) * 256 + c0 + ic;
#pragma unroll
  for (int j = 0; j < 16; ++j) {
    int wl = j * 4 + wg;
    op[wl * 256] = f2bf(lds[ic][wl]);
  }
}

// ------- modulate+demodulate weights: wmod[b][o][r*256+i] bf16 -------------------
__global__ __launch_bounds__(256) void k_modw(const float* __restrict__ W,
                                              const float* __restrict__ y,
                                              ushort* __restrict__ wmod) {
  __shared__ float red[256];
  const int b = blockIdx.x >> 8, o = blockIdx.x & 255, t = threadIdx.x;
  const float* wp = W + (size_t)(o * 256 + t) * 9;
  float wr[9];
#pragma unroll
  for (int r = 0; r < 9; ++r) wr[r] = wp[r];
  const float ym = y[b * 256 + t] + 1.0f;
  float ss = 0.f;
#pragma unroll
  for (int r = 0; r < 9; ++r) ss += wr[r] * wr[r];
  red[t] = ss * ym * ym;
  __syncthreads();
  for (int s = 128; s > 0; s >>= 1) {
    if (t < s) red[t] += red[t + s];
    __syncthreads();
  }
  const float sc = rsqrtf(red[0] + 1e-8f) * ym;
  ushort* op = wmod + (size_t)(b * 256 + o) * 2304 + t;
#pragma unroll
  for (int r = 0; r < 9; ++r) op[r * 256] = f2bf(wr[r] * sc);
}

// ---------------- implicit-GEMM conv: out[b][o][n] = sum_k wmod * im2col(xT) ----
__global__ __launch_bounds__(256, 2) void k_gemm(const ushort* __restrict__ wmod,
                                                 const ushort* __restrict__ xT,
                                                 const float* __restrict__ bias,
                                                 float* __restrict__ out) {
  __shared__ ushort ldsA[128 * 32];  // [o_row 0..127][k 0..31], 64B rows
  __shared__ ushort ldsB[128 * 32];  // [n_row 0..127][k 0..31]
  const int t = threadIdx.x;
  const int b = blockIdx.x >> 6;
  const int rem = blockIdx.x & 63;
  const int o0 = (rem & 1) << 7;   // 2 M-tiles of 128 cout
  const int tn = rem >> 1;         // 32 N-tiles of 128 spatial (= 2 image rows)
  const int n0 = tn << 7;
  const int h0 = tn << 1;
  const int l = t & 63, w = t >> 6;
  const int ln = l & 15, kq = l >> 4;
  const int wm = w >> 1, wn = w & 1;

  // staging pointers (bytes)
  const char* gA = (const char*)wmod + (size_t)b * WM_IMG_BYTES +
                   (size_t)(o0 + (t >> 2)) * WM_ROW_BYTES + (t & 3) * 16;
  const char* xTb = (const char*)xT + (size_t)b * XT_IMG_BYTES + (t & 3) * 16;
  const int wl = (t >> 2) & 63;  // w coordinate this thread stages for B

  f32x4 acc[4][4];
  const f32x4 z4 = {0.f, 0.f, 0.f, 0.f};
#pragma unroll
  for (int i = 0; i < 4; ++i)
#pragma unroll
    for (int j = 0; j < 4; ++j) acc[i][j] = z4;

  ushort* lA = ldsA + t * 8;
  ushort* lB = ldsB + t * 8;
  const ushort* rA = ldsA + (wm * 64 + ln) * 32 + kq * 8;
  const ushort* rB = ldsB + (wn * 64 + ln) * 32 + kq * 8;

#pragma unroll 1
  for (int r = 0; r < 9; ++r) {
    const int kh = r / 3, kw = r % 3;
    const char* gB = xTb + (((h0 + kh) * 66 + wl + kw) * 512);
#pragma unroll 1
    for (int s = 0; s < 8; ++s) {
      async16(lA, gA);
      async16(lA + 2048, gA + 64 * WM_ROW_BYTES);
      async16(lB, gB);
      async16(lB + 2048, gB + 66 * 512);
      asm volatile("s_waitcnt vmcnt(0)" ::: "memory");
      __syncthreads();
      short8 af[4], bf[4];
#pragma unroll
      for (int mi = 0; mi < 4; ++mi) af[mi] = *(const short8*)(rA + mi * 16 * 32);
#pragma unroll
      for (int ni = 0; ni < 4; ++ni) bf[ni] = *(const short8*)(rB + ni * 16 * 32);
#pragma unroll
      for (int mi = 0; mi < 4; ++mi)
#pragma unroll
        for (int ni = 0; ni < 4; ++ni)
          acc[mi][ni] = __builtin_amdgcn_mfma_f32_16x16x32_bf16(af[mi], bf[ni], acc[mi][ni], 0, 0, 0);
      __syncthreads();
      gA += 64;  // advance K by 32 bf16
      gB += 64;
    }
  }

  // epilogue: C row = o (row=(lane>>4)*4+reg), col = n (lane&15) — coalesced n stores
  float* outB = out + (size_t)(b * 256 + o0 + wm * 64) * 4096 + n0 + wn * 64 + ln;
#pragma unroll
  for (int mi = 0; mi < 4; ++mi) {
#pragma unroll
    for (int rg = 0; rg < 4; ++rg) {
      const int orow = mi * 16 + kq * 4 + rg;
      const float bv = bias[o0 + wm * 64 + orow];
      float* po = outB + (size_t)orow * 4096;
#pragma unroll
      for (int ni = 0; ni < 4; ++ni) po[ni * 16] = acc[mi][ni][rg] + bv;
    }
  }
}

extern "C" void kernel_launch(void* const* d_in, const int* in_sizes, int n_in,
                              void* d_out, int out_size, void* d_ws, size_t ws_size,
                              hipStream_t stream) {
  const float* x    = (const float*)d_in[0];   // [32,256,64,64]
  const float* y    = (const float*)d_in[1];   // [32,256]
  const float* W    = (const float*)d_in[2];   // [256,256,3,3]
  const float* bias = (const float*)d_in[3];   // [256]
  float* out = (float*)d_out;                  // [32,256,64,64]

  ushort* xT   = (ushort*)d_ws;                                  // 71,368,704 B
  ushort* wmod = (ushort*)((char*)d_ws + (size_t)XT_TOTAL_BYTES); // 37,748,736 B

  k_zero <<<XT_TOTAL_BYTES / (16 * 256), 256, 0, stream>>>((uint4*)d_ws);
  k_xpose<<<32 * 64 * 4, 256, 0, stream>>>(x, xT);
  k_modw <<<32 * 256,    256, 0, stream>>>(W, y, wmod);
  k_gemm <<<32 * 64,     256, 0, stream>>>(wmod, xT, bias, out);
}

// Round 2
// 419.877 us; speedup vs baseline: 1.1174x; 1.1174x over previous
//
#include <hip/hip_runtime.h>
#include <hip/hip_bf16.h>

typedef __attribute__((ext_vector_type(8))) short short8;
typedef __attribute__((ext_vector_type(4))) float f32x4;

#define XT_IMG_BYTES (66*66*256*2)       // 2,230,272 per sample
#define XT_TOTAL_BYTES (32*XT_IMG_BYTES) // 71,368,704
#define WM_ROW_BYTES (2304*2)            // 4608
#define WM_IMG_BYTES (256*WM_ROW_BYTES)  // 1,179,648

static __device__ __forceinline__ void async16(void* lds, const void* g) {
  __builtin_amdgcn_global_load_lds((const __attribute__((address_space(1))) void*)g,
                                   (__attribute__((address_space(3))) void*)lds, 16, 0, 0);
}
static __device__ __forceinline__ ushort f2bf(float f) {
  __hip_bfloat16 h = __float2bfloat16(f);
  return *reinterpret_cast<ushort*>(&h);
}

// ---------------- zero ONLY the pad border of xT (4.3 MB not 71 MB) -------------
__global__ __launch_bounds__(256) void k_zeroborder(uint4* __restrict__ xT4) {
  const int b = blockIdx.x;
  const int t = threadIdx.x;
  const uint4 z = make_uint4(0u, 0u, 0u, 0u);
  uint4* base = xT4 + (size_t)b * (66 * 66 * 32);  // 32 uint4 per pixel
  uint4* r0  = base;
  uint4* r65 = base + (size_t)65 * 66 * 32;
  for (int i = t; i < 2112; i += 256) { r0[i] = z; r65[i] = z; }  // rows 0 & 65
  for (int i = t; i < 2048; i += 256) {                            // cols 0 & 65
    int r = (i >> 5) + 1, c = i & 31;
    base[((size_t)r * 66 + 0)  * 32 + c] = z;
    base[((size_t)r * 66 + 65) * 32 + c] = z;
  }
}

// ---------------- x [b][c][h][w] fp32 -> xT [b][h+1][w+1][c] bf16 (interior) ----
__global__ __launch_bounds__(256) void k_xpose(const float* __restrict__ x,
                                               ushort* __restrict__ xT) {
  __shared__ float lds[64][65];
  const int bx = blockIdx.x;
  const int b  = bx >> 8;
  const int h  = (bx >> 2) & 63;
  const int c0 = (bx & 3) << 6;
  const int t  = threadIdx.x;
  const int tw = t & 63, tg = t >> 6;
  const float* xp = x + (size_t)(b * 256 + c0) * 4096 + h * 64 + tw;
#pragma unroll
  for (int j = 0; j < 16; ++j) {
    int il = j * 4 + tg;
    lds[il][tw] = xp[(size_t)il * 4096];
  }
  __syncthreads();
  const int q  = t & 15;   // channel-quad within the 64-channel group
  const int w0 = t >> 4;   // 0..15
  ushort* op = xT + (size_t)b * (66 * 66 * 256) + ((size_t)(h + 1) * 66 + 1) * 256 + c0;
#pragma unroll
  for (int j = 0; j < 4; ++j) {
    const int wl = j * 16 + w0;
    ushort4 v;
    v.x = f2bf(lds[4 * q + 0][wl]);
    v.y = f2bf(lds[4 * q + 1][wl]);
    v.z = f2bf(lds[4 * q + 2][wl]);
    v.w = f2bf(lds[4 * q + 3][wl]);
    *(ushort4*)(op + (size_t)wl * 256 + 4 * q) = v;  // 8B stores, 128B/16-lane seg
  }
}

// ------- modulate+demodulate weights: wmod[b][o][r*256+i] bf16 -------------------
__global__ __launch_bounds__(256) void k_modw(const float* __restrict__ W,
                                              const float* __restrict__ y,
                                              ushort* __restrict__ wmod) {
  __shared__ float red[256];
  const int b = blockIdx.x >> 8, o = blockIdx.x & 255, t = threadIdx.x;
  const float* wp = W + (size_t)(o * 256 + t) * 9;
  float wr[9];
#pragma unroll
  for (int r = 0; r < 9; ++r) wr[r] = wp[r];
  const float ym = y[b * 256 + t] + 1.0f;
  float ss = 0.f;
#pragma unroll
  for (int r = 0; r < 9; ++r) ss += wr[r] * wr[r];
  red[t] = ss * ym * ym;
  __syncthreads();
  for (int s = 128; s > 0; s >>= 1) {
    if (t < s) red[t] += red[t + s];
    __syncthreads();
  }
  const float sc = rsqrtf(red[0] + 1e-8f) * ym;
  ushort* op = wmod + (size_t)(b * 256 + o) * 2304 + t;
#pragma unroll
  for (int r = 0; r < 9; ++r) op[r * 256] = f2bf(wr[r] * sc);
}

// ---------------- implicit-GEMM conv: out[b][o][n] = sum_k wmod * im2col(xT) ----
// XCD swizzle: blocks of one sample pinned to one XCD so its 3.4 MB working set
// (wmod[b] 1.18 MB + streaming xT rows) stays L2-resident.
__global__ __launch_bounds__(256, 2) void k_gemm(const ushort* __restrict__ wmod,
                                                 const ushort* __restrict__ xT,
                                                 const float* __restrict__ bias,
                                                 float* __restrict__ out) {
  __shared__ ushort ldsA[128 * 32];  // [o_row 0..127][k 0..31]
  __shared__ ushort ldsB[128 * 32];  // [n_row 0..127][k 0..31]
  const int t = threadIdx.x;
  const int bx = blockIdx.x;
  const int xcd = bx & 7;            // hw round-robins consecutive blocks over XCDs
  const int idx = bx >> 3;           // 0..255
  const int b   = xcd + ((idx >> 6) << 3);  // 4 samples per XCD
  const int rem = idx & 63;
  const int o0 = (rem & 1) << 7;   // 2 M-tiles of 128 cout (pair shares B via L2)
  const int tn = rem >> 1;         // 32 N-tiles of 128 spatial (= 2 image rows)
  const int n0 = tn << 7;
  const int h0 = tn << 1;
  const int l = t & 63, w = t >> 6;
  const int ln = l & 15, kq = l >> 4;
  const int wm = w >> 1, wn = w & 1;

  const char* gA = (const char*)wmod + (size_t)b * WM_IMG_BYTES +
                   (size_t)(o0 + (t >> 2)) * WM_ROW_BYTES + (t & 3) * 16;
  const char* xTb = (const char*)xT + (size_t)b * XT_IMG_BYTES + (t & 3) * 16;
  const int wl = (t >> 2) & 63;

  f32x4 acc[4][4];
  const f32x4 z4 = {0.f, 0.f, 0.f, 0.f};
#pragma unroll
  for (int i = 0; i < 4; ++i)
#pragma unroll
    for (int j = 0; j < 4; ++j) acc[i][j] = z4;

  ushort* lA = ldsA + t * 8;
  ushort* lB = ldsB + t * 8;
  const ushort* rA = ldsA + (wm * 64 + ln) * 32 + kq * 8;
  const ushort* rB = ldsB + (wn * 64 + ln) * 32 + kq * 8;

#pragma unroll 1
  for (int r = 0; r < 9; ++r) {
    const int kh = r / 3, kw = r % 3;
    const char* gB = xTb + (((h0 + kh) * 66 + wl + kw) * 512);
#pragma unroll 1
    for (int s = 0; s < 8; ++s) {
      async16(lA, gA);
      async16(lA + 2048, gA + 64 * WM_ROW_BYTES);
      async16(lB, gB);
      async16(lB + 2048, gB + 66 * 512);
      asm volatile("s_waitcnt vmcnt(0)" ::: "memory");
      __syncthreads();
      short8 af[4], bf[4];
#pragma unroll
      for (int mi = 0; mi < 4; ++mi) af[mi] = *(const short8*)(rA + mi * 16 * 32);
#pragma unroll
      for (int ni = 0; ni < 4; ++ni) bf[ni] = *(const short8*)(rB + ni * 16 * 32);
#pragma unroll
      for (int mi = 0; mi < 4; ++mi)
#pragma unroll
        for (int ni = 0; ni < 4; ++ni)
          acc[mi][ni] = __builtin_amdgcn_mfma_f32_16x16x32_bf16(af[mi], bf[ni], acc[mi][ni], 0, 0, 0);
      __syncthreads();
      gA += 64;  // advance K by 32 bf16
      gB += 64;
    }
  }

  // epilogue: C row = o (row=(lane>>4)*4+reg), col = n (lane&15)
  float* outB = out + (size_t)(b * 256 + o0 + wm * 64) * 4096 + n0 + wn * 64 + ln;
#pragma unroll
  for (int mi = 0; mi < 4; ++mi) {
#pragma unroll
    for (int rg = 0; rg < 4; ++rg) {
      const int orow = mi * 16 + kq * 4 + rg;
      const float bv = bias[o0 + wm * 64 + orow];
      float* po = outB + (size_t)orow * 4096;
#pragma unroll
      for (int ni = 0; ni < 4; ++ni) po[ni * 16] = acc[mi][ni][rg] + bv;
    }
  }
}

extern "C" void kernel_launch(void* const* d_in, const int* in_sizes, int n_in,
                              void* d_out, int out_size, void* d_ws, size_t ws_size,
                              hipStream_t stream) {
  const float* x    = (const float*)d_in[0];   // [32,256,64,64]
  const float* y    = (const float*)d_in[1];   // [32,256]
  const float* W    = (const float*)d_in[2];   // [256,256,3,3]
  const float* bias = (const float*)d_in[3];   // [256]
  float* out = (float*)d_out;                  // [32,256,64,64]

  ushort* xT   = (ushort*)d_ws;                                   // 71,368,704 B
  ushort* wmod = (ushort*)((char*)d_ws + (size_t)XT_TOTAL_BYTES); // 37,748,736 B

  k_zeroborder<<<32,          256, 0, stream>>>((uint4*)d_ws);
  k_xpose     <<<32 * 64 * 4, 256, 0, stream>>>(x, xT);
  k_modw      <<<32 * 256,    256, 0, stream>>>(W, y, wmod);
  k_gemm      <<<32 * 64,     256, 0, stream>>>(wmod, xT, bias, out);
}